// Round 1
// baseline (210.159 us; speedup 1.0000x reference)
//
#include <hip/hip_runtime.h>

#define BATCH   4096
#define IN_DIM  1024
#define OUT_DIM 1024
#define NB      8                 // DEGREE + 1
#define NBK     7                 // basis funcs in the GEMM (d=1..7; d=0 is a bias)
#define KD2     (IN_DIM * NBK)    // 7168

typedef __bf16 bf16x8 __attribute__((ext_vector_type(8)));
typedef float  f32x4  __attribute__((ext_vector_type(4)));
typedef unsigned short us8 __attribute__((ext_vector_type(8)));

__device__ __forceinline__ unsigned short f2bf(float f) {
    unsigned int u = __float_as_uint(f);
    u += 0x7fffu + ((u >> 16) & 1u);   // round-to-nearest-even
    return (unsigned short)(u >> 16);
}

// fast tanh: 1 - 2/(e^{2x}+1) via v_exp_f32 + v_rcp_f32; exact limits at +-inf.
__device__ __forceinline__ float fast_tanh(float x) {
    const float LOG2E_X2 = 2.8853900817779268f;   // 2*log2(e)
    float e = __builtin_amdgcn_exp2f(x * LOG2E_X2);
    return 1.0f - 2.0f * __builtin_amdgcn_rcpf(e + 1.0f);
}

__device__ __forceinline__ void ld_lds16(const unsigned short* g, unsigned short* l) {
    __builtin_amdgcn_global_load_lds(
        (const __attribute__((address_space(1))) void*)g,
        (__attribute__((address_space(3))) void*)l, 16, 0, 0);
}

// ---------------------------------------------------------------------------
// Kernel 1 (fused, 3 block roles in one dispatch):  [UNCHANGED THIS ROUND]
//  [0, 16384):            basis prep  A[b][i*7+d-1] = bf16(P_d(tanh(x[b,i])))
//  [16384, 16896):        coeffs repack Bt[o][i*7+d-1] = bf16(coeffs[i][o][d])
//                         + exact fp32 bias partials bias_part[i/32][o]
//  [16896, 17920):        zero C (replaces the separate hipMemsetAsync)
// ---------------------------------------------------------------------------
#define PREP_BLOCKS   (BATCH * IN_DIM / 256)   // 16384
#define REPACK_BLOCKS 512
#define ZERO_BLOCKS   (BATCH * OUT_DIM / 4096) // 1024
#define TI 32
#define TO 64
#define RSTR 232    // LDS row stride (ushorts) per o: 224 data + 8 pad (16B-aligned)

__global__ __launch_bounds__(256) void prep_and_repack(
    const float* __restrict__ x, const float* __restrict__ ap,
    const float* __restrict__ qp, const float* __restrict__ coeffs,
    unsigned short* __restrict__ Aw, unsigned short* __restrict__ Bt,
    float* __restrict__ bias_part,   // [32][OUT_DIM]
    float* __restrict__ C) {
    __shared__ __align__(16) unsigned short lt[TO * RSTR + 512];  // 30.0 KB
    const int tid = threadIdx.x;

    if (blockIdx.x < PREP_BLOCKS) {
        // ---- basis prep: block covers (b, i0..i0+255) ----
        const int b  = blockIdx.x >> 2;
        const int i0 = (blockIdx.x & 3) << 8;
        const float a = ap[0], q = qp[0];
        const float xt = fast_tanh(x[(size_t)b * IN_DIM + i0 + tid]);
        float p[NB];
        p[0] = 1.0f;
        p[1] = xt - a;
        float qn = q, qn1 = 1.0f;
#pragma unroll
        for (int n = 2; n < NB; ++n) {
            qn *= q; qn1 *= q;
            p[n] = (xt - (a + qn)) * p[n - 1] - a * qn1 * p[n - 2];
        }
        // pack 7 bf16/thread via LDS, then 16B-coalesced global stores
#pragma unroll
        for (int d = 1; d < NB; ++d) lt[tid * 7 + (d - 1)] = f2bf(p[d]);
        __syncthreads();
        if (tid < 224) {   // 224 chunks x 16 B = 256*7 ushorts
            us8 v = *(const us8*)(lt + tid * 8);
            *(us8*)(Aw + (size_t)b * KD2 + i0 * 7 + tid * 8) = v;
        }
        return;
    }

    const int bid = blockIdx.x - PREP_BLOCKS;
    if (bid < REPACK_BLOCKS) {
        // ---- repack + bias partials: patch i0..i0+32 x o0..o0+64 ----
        const int g  = bid & 31;
        const int i0 = g * TI;
        const int o0 = (bid >> 5) * TO;
        const int o_local = tid & 63;
        float bpart = 0.f;
#pragma unroll
        for (int pass = 0; pass < 8; ++pass) {
            const int i_local = pass * 4 + (tid >> 6);
            const float* src = coeffs +
                ((size_t)(i0 + i_local) * OUT_DIM + (o0 + o_local)) * NB;
            float4 v0 = *(const float4*)src;
            float4 v1 = *(const float4*)(src + 4);
            bpart += v0.x;                       // d = 0 -> exact fp32 bias
            unsigned short* dst = lt + o_local * RSTR + i_local * 7;
            dst[0] = f2bf(v0.y); dst[1] = f2bf(v0.z); dst[2] = f2bf(v0.w);
            dst[3] = f2bf(v1.x); dst[4] = f2bf(v1.y); dst[5] = f2bf(v1.z);
            dst[6] = f2bf(v1.w);
        }
        float* sb = (float*)(lt + TO * RSTR);    // 256 floats
        sb[(tid >> 6) * 64 + o_local] = bpart;
        __syncthreads();
        if (tid < 64)
            bias_part[(size_t)g * OUT_DIM + o0 + tid] =
                sb[tid] + sb[64 + tid] + sb[128 + tid] + sb[192 + tid];
        // write phase: thread -> (o = tid>>2, chunk c = (tid&3)+4*pass)
#pragma unroll
        for (int pass = 0; pass < 7; ++pass) {
            const int o = tid >> 2;
            const int c = (tid & 3) + 4 * pass;  // 28 chunks x 16 B = 224 ushorts
            us8 v = *(const us8*)(lt + o * RSTR + c * 8);
            *(us8*)(Bt + (size_t)(o0 + o) * KD2 + i0 * 7 + c * 8) = v;
        }
        return;
    }

    // ---- zero C: 4096 floats per block ----
    const int z = bid - REPACK_BLOCKS;
    float* dst = C + (size_t)z * 4096 + tid * 4;
    const f32x4 zero = {0.f, 0.f, 0.f, 0.f};
#pragma unroll
    for (int j = 0; j < 4; ++j) *(f32x4*)(dst + j * 1024) = zero;
}

// ---------------------------------------------------------------------------
// Kernel 2: GEMM  C[M,N] += A[M,KD2] * Bt[N,KD2]^T  (bf16 -> fp32), now the
// 256x256 8-phase counted-vmcnt schedule (T2 swizzle + T3/T4 + T5 setprio).
//
// BM=BN=256, BK=64, 512 thr = 8 waves (2M x 4N), per-wave C = 128x64.
// LDS = 2 slots x (A 32KB + B 32KB) = 128 KiB dynamic, double-buffered.
// Split-K x4, atomicAdd into pre-zeroed C; ch==0 adds exact fp32 d=0 bias.
// Grid 256 blocks = 1/CU. XCD map: bidx&7 -> XCD; all 4 K-chunks of a tile
// share an XCD (atomics resolve in one L2); 2 m-tiles per XCD for A reuse.
//
// LDS swizzle (both-sides): row r, phys 16B-chunk s holds logical chunk
// s ^ (r&7); staging pre-swizzles the GLOBAL source, dest stays linear.
//
// Per K-tile, 4 phases; per phase: {2 x global_load_lds issue | ds_read
// subtile | setprio(1); 16 MFMA; setprio(0)}, raw s_barrier between phases,
// counted vmcnt (8 / 10) only twice per tile — never drained in the loop.
// Issue schedule (tile t): P0: A-loads L1,L3 of t+1; P1: B L0,L1 of t+2;
// P2: B L2,L3 of t+2; P3: A L0,L2 of t+2.  Region-safety: B slot free after
// P0; A rows [0,64)+[128,192) (L0,L2) free after P1; rows [64,128)+[192,256)
// (L1,L3) free after P3.  Wait math (2 loads/phase in flight):
//   W1 (P0): need B(t)+A L0,L2(t)  -> vmcnt(8)
//   W2 (P2): need A L1,L3(t)       -> vmcnt(10)
// Tail: out-of-range prefetches keep issuing (uniform counts) with the
// global SOURCE clamped to the last tile; dest regions are dead by then.
// ---------------------------------------------------------------------------
#define BM2 256
#define BN2 256
#define BK2 64
#define KSPLIT 4
#define KCH (KD2 / KSPLIT)   // 1792
#define NT  (KCH / BK2)      // 28 K-tiles per chunk
#define GEMM_LDS 131072

#define ISSUE_A(TT_, SL_, L_)                                                  \
    ld_lds16(gA + (size_t)(L_) * 64 * KD2 +                                    \
                 (size_t)((TT_) < NT ? (TT_) : (NT - 1)) * 64,                 \
             lds + (SL_) * 32768 + (L_) * 4096 + tid * 8)

#define ISSUE_B(TT_, SL_, L_)                                                  \
    ld_lds16(gB + (size_t)(L_) * 64 * KD2 +                                    \
                 (size_t)((TT_) < NT ? (TT_) : (NT - 1)) * 64,                 \
             lds + (SL_) * 32768 + 16384 + (L_) * 4096 + tid * 8)

#define PH_MFMA(SA_, MF_)                                                      \
    {                                                                          \
        bf16x8 a00 = *(const bf16x8*)((SA_) + aOff[(MF_)]);                    \
        bf16x8 a01 = *(const bf16x8*)((SA_) + (aOff[(MF_)] ^ 32));             \
        bf16x8 a10 = *(const bf16x8*)((SA_) + aOff[(MF_) + 1]);                \
        bf16x8 a11 = *(const bf16x8*)((SA_) + (aOff[(MF_) + 1] ^ 32));         \
        __builtin_amdgcn_s_setprio(1);                                         \
        _Pragma("unroll") for (int nf = 0; nf < 4; ++nf) {                     \
            acc[(MF_)][nf] = __builtin_amdgcn_mfma_f32_16x16x32_bf16(          \
                a00, bF[nf][0], acc[(MF_)][nf], 0, 0, 0);                      \
            acc[(MF_)][nf] = __builtin_amdgcn_mfma_f32_16x16x32_bf16(          \
                a01, bF[nf][1], acc[(MF_)][nf], 0, 0, 0);                      \
            acc[(MF_) + 1][nf] = __builtin_amdgcn_mfma_f32_16x16x32_bf16(      \
                a10, bF[nf][0], acc[(MF_) + 1][nf], 0, 0, 0);                  \
            acc[(MF_) + 1][nf] = __builtin_amdgcn_mfma_f32_16x16x32_bf16(      \
                a11, bF[nf][1], acc[(MF_) + 1][nf], 0, 0, 0);                  \
        }                                                                      \
        __builtin_amdgcn_s_setprio(0);                                         \
    }

#define TILE_BODY(T_, P_)                                                      \
    {                                                                          \
        const unsigned short* sA = lds + (P_) * 32768;                         \
        const unsigned short* sB = sA + 16384;                                 \
        /* ---- P0 ---- */                                                     \
        asm volatile("s_waitcnt vmcnt(8)" ::: "memory");                       \
        __builtin_amdgcn_s_barrier();                                          \
        ISSUE_A((T_) + 1, (P_) ^ 1, 1);                                        \
        ISSUE_A((T_) + 1, (P_) ^ 1, 3);                                        \
        _Pragma("unroll") for (int nf = 0; nf < 4; ++nf) {                     \
            bF[nf][0] = *(const bf16x8*)(sB + bOff[nf]);                       \
            bF[nf][1] = *(const bf16x8*)(sB + (bOff[nf] ^ 32));                \
        }                                                                      \
        PH_MFMA(sA, 0)                                                         \
        /* ---- P1 ---- */                                                     \
        __builtin_amdgcn_s_barrier();                                          \
        ISSUE_B((T_) + 2, (P_), 0);                                            \
        ISSUE_B((T_) + 2, (P_), 1);                                            \
        PH_MFMA(sA, 2)                                                         \
        /* ---- P2 ---- */                                                     \
        asm volatile("s_waitcnt vmcnt(10)" ::: "memory");                      \
        __builtin_amdgcn_s_barrier();                                          \
        ISSUE_B((T_) + 2, (P_), 2);                                            \
        ISSUE_B((T_) + 2, (P_), 3);                                            \
        PH_MFMA(sA, 4)                                                         \
        /* ---- P3 ---- */                                                     \
        __builtin_amdgcn_s_barrier();                                          \
        ISSUE_A((T_) + 2, (P_), 0);                                            \
        ISSUE_A((T_) + 2, (P_), 2);                                            \
        PH_MFMA(sA, 6)                                                         \
    }

__global__ __launch_bounds__(512, 2) void gemm_kernel(
    const unsigned short* __restrict__ A,    // bf16 bits [BATCH][KD2]
    const unsigned short* __restrict__ Bt,   // bf16 bits [OUT_DIM][KD2]
    const float* __restrict__ bias_part,     // [32][OUT_DIM]
    float* __restrict__ C) {                 // [BATCH][OUT_DIM], pre-zeroed
    extern __shared__ __align__(16) unsigned short lds[];  // 128 KiB dynamic

    const int tid  = threadIdx.x;
    const int bidx = blockIdx.x;
    const int xcd = bidx & 7;
    const int g   = bidx >> 3;
    const int m0 = (xcd * 2 + (g & 1)) * BM2;
    const int n0 = ((g >> 1) & 3) * BN2;
    const int ch = g >> 3;
    const size_t kb = (size_t)ch * KCH;

    const int lane  = tid & 63;
    const int w     = tid >> 6;
    const int wmG   = (w >> 2) * 128;   // wave m-offset within tile (0 / 128)
    const int wnG   = (w & 3) * 64;     // wave n-offset within tile
    const int row16 = lane & 15;
    const int quad  = lane >> 4;

    // ds_read element offsets (kk=0); kk=1 flips logical chunk via ^32 elems.
    int aOff[8], bOff[4];
#pragma unroll
    for (int mf = 0; mf < 8; ++mf) {
        int r = wmG + mf * 16 + row16;
        aOff[mf] = r * 64 + ((quad ^ (r & 7)) * 8);
    }
#pragma unroll
    for (int nf = 0; nf < 4; ++nf) {
        int c = wnG + nf * 16 + row16;
        bOff[nf] = c * 64 + ((quad ^ (c & 7)) * 8);
    }

    // Staging: load L covers rows [64L, 64L+64); thread t -> row rst=t>>3,
    // phys chunk s0=t&7; global source pre-swizzled: logical chunk s0^(rst&7).
    const int rst = tid >> 3;
    const int sw  = ((tid & 7) ^ (rst & 7)) * 8;
    const unsigned short* gA = A  + (size_t)(m0 + rst) * KD2 + kb + sw;
    const unsigned short* gB = Bt + (size_t)(n0 + rst) * KD2 + kb + sw;

    f32x4  acc[8][4] = {};
    bf16x8 bF[4][2];

    // Prologue: 14 loads, in the exact order the wait counts assume:
    // B(0)L0..L3, A(0)L0, A(0)L2, A(0)L1, A(0)L3, B(1)L0..L3, A(1)L0, A(1)L2.
    ISSUE_B(0, 0, 0); ISSUE_B(0, 0, 1); ISSUE_B(0, 0, 2); ISSUE_B(0, 0, 3);
    ISSUE_A(0, 0, 0); ISSUE_A(0, 0, 2); ISSUE_A(0, 0, 1); ISSUE_A(0, 0, 3);
    ISSUE_B(1, 1, 0); ISSUE_B(1, 1, 1); ISSUE_B(1, 1, 2); ISSUE_B(1, 1, 3);
    ISSUE_A(1, 1, 0); ISSUE_A(1, 1, 2);

#pragma unroll 1
    for (int t = 0; t < NT; t += 2) {
        TILE_BODY(t, 0)
        TILE_BODY(t + 1, 1)
    }

    // Drain dummy tail prefetches before reusing LDS / ending.
    asm volatile("s_waitcnt vmcnt(0)" ::: "memory");
    __syncthreads();

    // ch==0 folds in the exact d=0 bias: sbias[col] = sum_g bias_part[g][col]
    float* sbf = (float*)lds;
    if (ch == 0) {
        if (tid < 256) {
            float s = 0.f;
#pragma unroll
            for (int gg = 0; gg < 32; ++gg)
                s += bias_part[(size_t)gg * OUT_DIM + n0 + tid];
            sbf[tid] = s;
        }
        __syncthreads();
    }

    // C/D layout (m89-verified): col = lane&15, row = quad*4 + reg
#pragma unroll
    for (int mf = 0; mf < 8; ++mf) {
        const int rbase = m0 + wmG + mf * 16 + quad * 4;
#pragma unroll
        for (int nf = 0; nf < 4; ++nf) {
            const int col = n0 + wnG + nf * 16 + row16;
            const float bv = (ch == 0) ? sbf[wnG + nf * 16 + row16] : 0.f;
#pragma unroll
            for (int r = 0; r < 4; ++r)
                atomicAdd(&C[(size_t)(rbase + r) * OUT_DIM + col],
                          acc[mf][nf][r] + bv);
        }
    }
}

// ---------------------------------------------------------------------------
// Fallback (only if ws too small): fp32, block per batch row, basis in LDS.
// ---------------------------------------------------------------------------
__global__ __launch_bounds__(256) void fallback_kernel(
    const float* __restrict__ x, const float* __restrict__ ap,
    const float* __restrict__ qp, const float* __restrict__ coeffs,
    float* __restrict__ out) {
    __shared__ float sb[IN_DIM][NB];   // 32 KB
    const int b = blockIdx.x;
    const float a = ap[0], q = qp[0];
    for (int i = threadIdx.x; i < IN_DIM; i += 256) {
        float xt = fast_tanh(x[(size_t)b * IN_DIM + i]);
        float p0 = 1.0f, p1 = xt - a;
        sb[i][0] = p0; sb[i][1] = p1;
        float qn = q, qn1 = 1.0f;
#pragma unroll
        for (int n = 2; n < NB; ++n) {
            qn *= q; qn1 *= q;
            float p2 = (xt - (a + qn)) * p1 - a * qn1 * p0;
            sb[i][n] = p2;
            p0 = p1; p1 = p2;
        }
    }
    __syncthreads();
    float acc[4] = {0.f, 0.f, 0.f, 0.f};
    for (int i = 0; i < IN_DIM; ++i) {
        float bb[NB];
#pragma unroll
        for (int d = 0; d < NB; ++d) bb[d] = sb[i][d];
#pragma unroll
        for (int j = 0; j < 4; ++j) {
            int o = threadIdx.x + j * 256;
            const float* cf = coeffs + ((size_t)i * OUT_DIM + o) * NB;
            float s = 0.f;
#pragma unroll
            for (int d = 0; d < NB; ++d) s += bb[d] * cf[d];
            acc[j] += s;
        }
    }
#pragma unroll
    for (int j = 0; j < 4; ++j)
        out[(size_t)b * OUT_DIM + threadIdx.x + j * 256] = acc[j];
}

// ---------------------------------------------------------------------------
extern "C" void kernel_launch(void* const* d_in, const int* in_sizes, int n_in,
                              void* d_out, int out_size, void* d_ws, size_t ws_size,
                              hipStream_t stream) {
    const float* x      = (const float*)d_in[0];
    const float* a      = (const float*)d_in[1];
    const float* q      = (const float*)d_in[2];
    const float* coeffs = (const float*)d_in[3];
    float* out = (float*)d_out;

    const size_t needA = (size_t)BATCH * KD2 * sizeof(unsigned short);   // 56 MB
    const size_t needB = (size_t)OUT_DIM * KD2 * sizeof(unsigned short); // 14 MB
    const size_t needBias = 32 * (size_t)OUT_DIM * sizeof(float);        // 128 KB

    if (ws_size >= needA + needB + needBias) {
        static bool lds_attr_set = false;
        if (!lds_attr_set) {
            (void)hipFuncSetAttribute(
                reinterpret_cast<const void*>(&gemm_kernel),
                hipFuncAttributeMaxDynamicSharedMemorySize, GEMM_LDS);
            lds_attr_set = true;
        }
        unsigned short* Aw = (unsigned short*)d_ws;
        unsigned short* Bt = Aw + (size_t)BATCH * KD2;
        float* bias_part = (float*)((char*)d_ws + needA + needB);
        prep_and_repack<<<PREP_BLOCKS + REPACK_BLOCKS + ZERO_BLOCKS, 256, 0, stream>>>(
            x, a, q, coeffs, Aw, Bt, bias_part, out);
        gemm_kernel<<<(BATCH / BM2) * (OUT_DIM / BN2) * KSPLIT, 512, GEMM_LDS, stream>>>(
            Aw, Bt, bias_part, out);
    } else {
        fallback_kernel<<<BATCH, 256, 0, stream>>>(x, a, q, coeffs, out);
    }
}

// Round 2
// 200.234 us; speedup vs baseline: 1.0496x; 1.0496x over previous
//
#include <hip/hip_runtime.h>

#define BATCH   4096
#define IN_DIM  1024
#define OUT_DIM 1024
#define NB      8                 // DEGREE + 1
#define NBK     7                 // basis funcs in the GEMM (d=1..7; d=0 is a bias)
#define KD2     (IN_DIM * NBK)    // 7168
// Workspace K-layout (NEW this round, d-major): k = (d-1)*IN_DIM + i.
// Applied to BOTH A and Bt, so the GEMM is unaffected.

typedef __bf16 bf16x8 __attribute__((ext_vector_type(8)));
typedef float  f32x4  __attribute__((ext_vector_type(4)));
typedef unsigned short us8 __attribute__((ext_vector_type(8)));
typedef unsigned short us4 __attribute__((ext_vector_type(4)));

__device__ __forceinline__ unsigned short f2bf(float f) {
    unsigned int u = __float_as_uint(f);
    u += 0x7fffu + ((u >> 16) & 1u);   // round-to-nearest-even
    return (unsigned short)(u >> 16);
}

// fast tanh: 1 - 2/(e^{2x}+1) via v_exp_f32 + v_rcp_f32; exact limits at +-inf.
__device__ __forceinline__ float fast_tanh(float x) {
    const float LOG2E_X2 = 2.8853900817779268f;   // 2*log2(e)
    float e = __builtin_amdgcn_exp2f(x * LOG2E_X2);
    return 1.0f - 2.0f * __builtin_amdgcn_rcpf(e + 1.0f);
}

__device__ __forceinline__ void ld_lds16(const unsigned short* g, unsigned short* l) {
    __builtin_amdgcn_global_load_lds(
        (const __attribute__((address_space(1))) void*)g,
        (__attribute__((address_space(3))) void*)l, 16, 0, 0);
}

// 32-bit LDS offset of a generic pointer that points into LDS.
__device__ __forceinline__ unsigned lds_off(const void* p) {
    return (unsigned)(unsigned long long)
        (const __attribute__((address_space(3))) void*)p;
}

// Inline-asm ds_read_b128: opaque to SIInsertWaitcnts, so the compiler cannot
// insert conservative vmcnt waits against in-flight global_load_lds (LDS-DMA).
// We order it ourselves: barrier -> s_waitcnt lgkmcnt(0) -> sched_barrier(0).
template <int OFF>
__device__ __forceinline__ bf16x8 dsr128(unsigned addr) {
    f32x4 r;
    asm volatile("ds_read_b128 %0, %1 offset:%c2"
                 : "=v"(r) : "v"(addr), "i"(OFF));
    union { f32x4 f; bf16x8 h; } u; u.f = r; return u.h;
}

// ---------------------------------------------------------------------------
// Kernel 1 (fused, 3 block roles in one dispatch):
//  [0, 4096):        basis prep, one block per batch row. float4 loads,
//                    4-wide recurrence, 7x coalesced us4 stores (d-major, no LDS).
//  [4096, 4608):     coeffs repack (d-major writes) + exact fp32 bias partials
//  [4608, 5632):     zero C
// ---------------------------------------------------------------------------
#define PREP_BLOCKS   BATCH                    // 4096
#define REPACK_BLOCKS 512
#define ZERO_BLOCKS   (BATCH * OUT_DIM / 4096) // 1024
#define TI 32
#define TO 64
#define RSTR 232    // LDS row stride (ushorts) per o: 224 data + 8 pad (16B-aligned)

__global__ __launch_bounds__(256) void prep_and_repack(
    const float* __restrict__ x, const float* __restrict__ ap,
    const float* __restrict__ qp, const float* __restrict__ coeffs,
    unsigned short* __restrict__ Aw, unsigned short* __restrict__ Bt,
    float* __restrict__ bias_part,   // [32][OUT_DIM]
    float* __restrict__ C) {
    __shared__ __align__(16) unsigned short lt[TO * RSTR + 512];  // 30.0 KB
    const int tid = threadIdx.x;

    if (blockIdx.x < PREP_BLOCKS) {
        // ---- basis prep: block = one batch row; thread covers i = 4t..4t+4 ----
        const int b = blockIdx.x;
        const float a = ap[0], q = qp[0];
        float4 xv = *(const float4*)(x + (size_t)b * IN_DIM + tid * 4);
        float xe[4] = {xv.x, xv.y, xv.z, xv.w};
        float pm2[4], pm1[4];
        us4 ov;
#pragma unroll
        for (int e = 0; e < 4; ++e) {
            xe[e] = fast_tanh(xe[e]);
            pm2[e] = 1.0f;
            pm1[e] = xe[e] - a;
            ov[e] = f2bf(pm1[e]);
        }
        unsigned short* arow = Aw + (size_t)b * KD2 + tid * 4;
        *(us4*)arow = ov;                           // d=1 at k-offset 0
        float qn = q, qn1 = 1.0f;
#pragma unroll
        for (int n = 2; n < NB; ++n) {
            qn *= q; qn1 *= q;
#pragma unroll
            for (int e = 0; e < 4; ++e) {
                float pn = (xe[e] - (a + qn)) * pm1[e] - a * qn1 * pm2[e];
                pm2[e] = pm1[e]; pm1[e] = pn;
                ov[e] = f2bf(pn);
            }
            *(us4*)(arow + (size_t)(n - 1) * IN_DIM) = ov;
        }
        return;
    }

    const int bid = blockIdx.x - PREP_BLOCKS;
    if (bid < REPACK_BLOCKS) {
        // ---- repack + bias partials: patch i0..i0+32 x o0..o0+64 ----
        const int g  = bid & 31;
        const int i0 = g * TI;
        const int o0 = (bid >> 5) * TO;
        const int o_local = tid & 63;
        float bpart = 0.f;
#pragma unroll
        for (int pass = 0; pass < 8; ++pass) {
            const int i_local = pass * 4 + (tid >> 6);
            const float* src = coeffs +
                ((size_t)(i0 + i_local) * OUT_DIM + (o0 + o_local)) * NB;
            float4 v0 = *(const float4*)src;
            float4 v1 = *(const float4*)(src + 4);
            bpart += v0.x;                       // d = 0 -> exact fp32 bias
            // LDS stage, d-major per o: lt[o][d-1][i_local] (stride 32 per d)
            unsigned short* dst = lt + o_local * RSTR + i_local;
            dst[0]   = f2bf(v0.y); dst[32]  = f2bf(v0.z); dst[64]  = f2bf(v0.w);
            dst[96]  = f2bf(v1.x); dst[128] = f2bf(v1.y); dst[160] = f2bf(v1.z);
            dst[192] = f2bf(v1.w);
        }
        float* sb = (float*)(lt + TO * RSTR);    // 256 floats
        sb[(tid >> 6) * 64 + o_local] = bpart;
        __syncthreads();
        if (tid < 64)
            bias_part[(size_t)g * OUT_DIM + o0 + tid] =
                sb[tid] + sb[64 + tid] + sb[128 + tid] + sb[192 + tid];
        // write phase: thread -> (o = tid>>2, c = tid&3); 7 d-groups of 64B
#pragma unroll
        for (int p = 0; p < 7; ++p) {
            const int o = tid >> 2;
            const int c = tid & 3;
            us8 v = *(const us8*)(lt + o * RSTR + p * 32 + c * 8);
            *(us8*)(Bt + (size_t)(o0 + o) * KD2 + (size_t)p * IN_DIM + i0 + c * 8) = v;
        }
        return;
    }

    // ---- zero C: 4096 floats per block ----
    const int z = bid - REPACK_BLOCKS;
    float* dst = C + (size_t)z * 4096 + tid * 4;
    const f32x4 zero = {0.f, 0.f, 0.f, 0.f};
#pragma unroll
    for (int j = 0; j < 4; ++j) *(f32x4*)(dst + j * 1024) = zero;
}

// ---------------------------------------------------------------------------
// Kernel 2: GEMM  C[M,N] += A[M,KD2] * Bt[N,KD2]^T  (bf16 -> fp32),
// 256x256 8-phase schedule, now m201-faithful:
//   per phase: {asm ds_read frags | 2x global_load_lds issue}
//              s_barrier(a); s_waitcnt lgkmcnt(0); sched_barrier(0);
//              setprio(1); 16 MFMA; setprio(0); sched_barrier(0);
//              [P1: vmcnt(10) | P3: vmcnt(8)]; s_barrier(b)
// ds_reads are inline asm so the compiler cannot graft conservative vmcnt
// waits (LDS-DMA aliasing) onto them — the counted-vmcnt pipeline survives.
//
// LDS layout: [A slot0 32K][A slot1 32K][B slot0 32K][B slot1 32K] bytes.
// Swizzle unchanged: row r, phys chunk s holds logical chunk s^(r&7)
// (pre-swizzled global source, linear LDS dest).
//
// Issue schedule (tile t, slot P=t&1): P0: A(t+1)L1,L3 -> slot P^1;
// P1: B(t+2)L0,L1 -> slot P; P2: B(t+2)L2,L3 -> slot P; P3: A(t+2)L0,L2 -> P.
// Region safety: B slot-P free after P0(b); A L0,L2 free after P1(b);
// A L1,L3 free after P3(b).  Wait derivation (2 loads/phase):
//   P1-wait: queue 12, retire A(t)L1,L3   -> vmcnt(10)
//   P3-wait: queue 14, retire B(t+1)x4 + A(t+1)L0,L2 -> vmcnt(8)
// Tail prefetches clamp the SOURCE to tile NT-1 (uniform counts; dest
// regions are dead per the same schedule); epilogue drains vmcnt(0).
// ---------------------------------------------------------------------------
#define BM2 256
#define BN2 256
#define BK2 64
#define KSPLIT 4
#define KCH (KD2 / KSPLIT)   // 1792
#define NT  (KCH / BK2)      // 28 K-tiles per chunk
#define GEMM_LDS 131072

#define ISSUE_A(TT_, SL_, L_)                                                  \
    ld_lds16(gA + (size_t)(L_) * 64 * KD2 +                                    \
                 (size_t)((TT_) < NT ? (TT_) : (NT - 1)) * 64,                 \
             lds + (SL_) * 16384 + (L_) * 4096 + tid * 8)

#define ISSUE_B(TT_, SL_, L_)                                                  \
    ld_lds16(gB + (size_t)(L_) * 64 * KD2 +                                    \
                 (size_t)((TT_) < NT ? (TT_) : (NT - 1)) * 64,                 \
             lds + 32768 + (SL_) * 16384 + (L_) * 4096 + tid * 8)

#define BARRIER_A()                                                            \
    __builtin_amdgcn_s_barrier();                                              \
    asm volatile("s_waitcnt lgkmcnt(0)" ::: "memory");                         \
    __builtin_amdgcn_sched_barrier(0);

#define MFMA16(M_, A0_, A1_, A2_, A3_)                                         \
    __builtin_amdgcn_s_setprio(1);                                             \
    _Pragma("unroll") for (int nf = 0; nf < 4; ++nf) {                         \
        acc[M_][nf] = __builtin_amdgcn_mfma_f32_16x16x32_bf16(                 \
            A0_, bF[nf][0], acc[M_][nf], 0, 0, 0);                             \
        acc[M_][nf] = __builtin_amdgcn_mfma_f32_16x16x32_bf16(                 \
            A1_, bF[nf][1], acc[M_][nf], 0, 0, 0);                             \
        acc[(M_) + 1][nf] = __builtin_amdgcn_mfma_f32_16x16x32_bf16(           \
            A2_, bF[nf][0], acc[(M_) + 1][nf], 0, 0, 0);                       \
        acc[(M_) + 1][nf] = __builtin_amdgcn_mfma_f32_16x16x32_bf16(           \
            A3_, bF[nf][1], acc[(M_) + 1][nf], 0, 0, 0);                       \
    }                                                                          \
    __builtin_amdgcn_s_setprio(0);                                             \
    __builtin_amdgcn_sched_barrier(0);

#define TILE_BODY(T_, P_)                                                      \
    {                                                                          \
        constexpr int OFF = (P_) * 32768;                                      \
        { /* ---- P0 ---- */                                                   \
            bf16x8 a0 = dsr128<OFF>(aA[0]), a1 = dsr128<OFF>(aA[0] ^ 64);      \
            bf16x8 a2 = dsr128<OFF>(aA[1]), a3 = dsr128<OFF>(aA[1] ^ 64);      \
            _Pragma("unroll") for (int nf = 0; nf < 4; ++nf) {                 \
                bF[nf][0] = dsr128<OFF>(bA[nf]);                               \
                bF[nf][1] = dsr128<OFF>(bA[nf] ^ 64);                          \
            }                                                                  \
            ISSUE_A((T_) + 1, (P_) ^ 1, 1);                                    \
            ISSUE_A((T_) + 1, (P_) ^ 1, 3);                                    \
            BARRIER_A()                                                        \
            MFMA16(0, a0, a1, a2, a3)                                          \
            __builtin_amdgcn_s_barrier();                                      \
        }                                                                      \
        { /* ---- P1 ---- */                                                   \
            bf16x8 a0 = dsr128<OFF>(aA[2]), a1 = dsr128<OFF>(aA[2] ^ 64);      \
            bf16x8 a2 = dsr128<OFF>(aA[3]), a3 = dsr128<OFF>(aA[3] ^ 64);      \
            ISSUE_B((T_) + 2, (P_), 0);                                        \
            ISSUE_B((T_) + 2, (P_), 1);                                        \
            BARRIER_A()                                                        \
            MFMA16(2, a0, a1, a2, a3)                                          \
            asm volatile("s_waitcnt vmcnt(10)" ::: "memory");                  \
            __builtin_amdgcn_s_barrier();                                      \
        }                                                                      \
        { /* ---- P2 ---- */                                                   \
            bf16x8 a0 = dsr128<OFF>(aA[4]), a1 = dsr128<OFF>(aA[4] ^ 64);      \
            bf16x8 a2 = dsr128<OFF>(aA[5]), a3 = dsr128<OFF>(aA[5] ^ 64);      \
            ISSUE_B((T_) + 2, (P_), 2);                                        \
            ISSUE_B((T_) + 2, (P_), 3);                                        \
            BARRIER_A()                                                        \
            MFMA16(4, a0, a1, a2, a3)                                          \
            __builtin_amdgcn_s_barrier();                                      \
        }                                                                      \
        { /* ---- P3 ---- */                                                   \
            bf16x8 a0 = dsr128<OFF>(aA[6]), a1 = dsr128<OFF>(aA[6] ^ 64);      \
            bf16x8 a2 = dsr128<OFF>(aA[7]), a3 = dsr128<OFF>(aA[7] ^ 64);      \
            ISSUE_A((T_) + 2, (P_), 0);                                        \
            ISSUE_A((T_) + 2, (P_), 2);                                        \
            BARRIER_A()                                                        \
            MFMA16(6, a0, a1, a2, a3)                                          \
            asm volatile("s_waitcnt vmcnt(8)" ::: "memory");                   \
            __builtin_amdgcn_s_barrier();                                      \
        }                                                                      \
    }

__global__ __launch_bounds__(512, 2) void gemm_kernel(
    const unsigned short* __restrict__ A,    // bf16 bits [BATCH][KD2]
    const unsigned short* __restrict__ Bt,   // bf16 bits [OUT_DIM][KD2]
    const float* __restrict__ bias_part,     // [32][OUT_DIM]
    float* __restrict__ C) {                 // [BATCH][OUT_DIM], pre-zeroed
    extern __shared__ __align__(16) unsigned short lds[];  // 128 KiB dynamic

    const int tid  = threadIdx.x;
    const int bidx = blockIdx.x;
    const int xcd = bidx & 7;
    const int g   = bidx >> 3;
    const int m0 = (xcd * 2 + (g & 1)) * BM2;
    const int n0 = ((g >> 1) & 3) * BN2;
    const int ch = g >> 3;
    const size_t kb = (size_t)ch * KCH;

    const int lane  = tid & 63;
    const int w     = tid >> 6;
    const int wmG   = (w >> 2) * 128;   // wave m-offset within tile (0 / 128)
    const int wnG   = (w & 3) * 64;     // wave n-offset within tile
    const int row16 = lane & 15;
    const int quad  = lane >> 4;

    // LDS byte addresses of fragments (slot 0; slot 1 via offset:32768).
    const unsigned ldsb = lds_off(lds);
    unsigned aA[8], bA[4];
#pragma unroll
    for (int mf = 0; mf < 8; ++mf) {
        int r = wmG + mf * 16 + row16;
        aA[mf] = ldsb + 2u * (unsigned)(r * 64 + ((quad ^ (r & 7)) * 8));
    }
#pragma unroll
    for (int nf = 0; nf < 4; ++nf) {
        int c = wnG + nf * 16 + row16;
        bA[nf] = ldsb + 65536u + 2u * (unsigned)(c * 64 + ((quad ^ (c & 7)) * 8));
    }

    // Staging: load L covers rows [64L, 64L+64); thread t -> row rst=t>>3,
    // phys chunk s0=t&7; global source pre-swizzled: logical chunk s0^(rst&7).
    const int rst = tid >> 3;
    const int sw  = ((tid & 7) ^ (rst & 7)) * 8;
    const unsigned short* gA = A  + (size_t)(m0 + rst) * KD2 + kb + sw;
    const unsigned short* gB = Bt + (size_t)(n0 + rst) * KD2 + kb + sw;

    f32x4  acc[8][4] = {};
    bf16x8 bF[4][2];

    // Prologue: 14 loads in the exact order the wait counts assume.
    ISSUE_B(0, 0, 0); ISSUE_B(0, 0, 1); ISSUE_B(0, 0, 2); ISSUE_B(0, 0, 3);
    ISSUE_A(0, 0, 0); ISSUE_A(0, 0, 2);
    ISSUE_A(0, 0, 1); ISSUE_A(0, 0, 3);
    ISSUE_B(1, 1, 0); ISSUE_B(1, 1, 1); ISSUE_B(1, 1, 2); ISSUE_B(1, 1, 3);
    ISSUE_A(1, 1, 0); ISSUE_A(1, 1, 2);
    asm volatile("s_waitcnt vmcnt(8)" ::: "memory");
    __builtin_amdgcn_s_barrier();

#pragma unroll 1
    for (int t = 0; t < NT; t += 2) {
        TILE_BODY(t, 0)
        TILE_BODY(t + 1, 1)
    }

    // Drain dummy tail prefetches before reusing LDS / ending.
    asm volatile("s_waitcnt vmcnt(0)" ::: "memory");
    __syncthreads();

    // ch==0 folds in the exact d=0 bias: sbias[col] = sum_g bias_part[g][col]
    float* sbf = (float*)lds;
    if (ch == 0) {
        if (tid < 256) {
            float s = 0.f;
#pragma unroll
            for (int gg = 0; gg < 32; ++gg)
                s += bias_part[(size_t)gg * OUT_DIM + n0 + tid];
            sbf[tid] = s;
        }
        __syncthreads();
    }

    // C/D layout (m89-verified): col = lane&15, row = quad*4 + reg
#pragma unroll
    for (int mf = 0; mf < 8; ++mf) {
        const int rbase = m0 + wmG + mf * 16 + quad * 4;
#pragma unroll
        for (int nf = 0; nf < 4; ++nf) {
            const int col = n0 + wnG + nf * 16 + row16;
            const float bv = (ch == 0) ? sbf[wnG + nf * 16 + row16] : 0.f;
#pragma unroll
            for (int r = 0; r < 4; ++r)
                atomicAdd(&C[(size_t)(rbase + r) * OUT_DIM + col],
                          acc[mf][nf][r] + bv);
        }
    }
}

// ---------------------------------------------------------------------------
// Fallback (only if ws too small): fp32, block per batch row, basis in LDS.
// ---------------------------------------------------------------------------
__global__ __launch_bounds__(256) void fallback_kernel(
    const float* __restrict__ x, const float* __restrict__ ap,
    const float* __restrict__ qp, const float* __restrict__ coeffs,
    float* __restrict__ out) {
    __shared__ float sb[IN_DIM][NB];   // 32 KB
    const int b = blockIdx.x;
    const float a = ap[0], q = qp[0];
    for (int i = threadIdx.x; i < IN_DIM; i += 256) {
        float xt = fast_tanh(x[(size_t)b * IN_DIM + i]);
        float p0 = 1.0f, p1 = xt - a;
        sb[i][0] = p0; sb[i][1] = p1;
        float qn = q, qn1 = 1.0f;
#pragma unroll
        for (int n = 2; n < NB; ++n) {
            qn *= q; qn1 *= q;
            float p2 = (xt - (a + qn)) * p1 - a * qn1 * p0;
            sb[i][n] = p2;
            p0 = p1; p1 = p2;
        }
    }
    __syncthreads();
    float acc[4] = {0.f, 0.f, 0.f, 0.f};
    for (int i = 0; i < IN_DIM; ++i) {
        float bb[NB];
#pragma unroll
        for (int d = 0; d < NB; ++d) bb[d] = sb[i][d];
#pragma unroll
        for (int j = 0; j < 4; ++j) {
            int o = threadIdx.x + j * 256;
            const float* cf = coeffs + ((size_t)i * OUT_DIM + o) * NB;
            float s = 0.f;
#pragma unroll
            for (int d = 0; d < NB; ++d) s += bb[d] * cf[d];
            acc[j] += s;
        }
    }
#pragma unroll
    for (int j = 0; j < 4; ++j)
        out[(size_t)b * OUT_DIM + threadIdx.x + j * 256] = acc[j];
}

// ---------------------------------------------------------------------------
extern "C" void kernel_launch(void* const* d_in, const int* in_sizes, int n_in,
                              void* d_out, int out_size, void* d_ws, size_t ws_size,
                              hipStream_t stream) {
    const float* x      = (const float*)d_in[0];
    const float* a      = (const float*)d_in[1];
    const float* q      = (const float*)d_in[2];
    const float* coeffs = (const float*)d_in[3];
    float* out = (float*)d_out;

    const size_t needA = (size_t)BATCH * KD2 * sizeof(unsigned short);   // 56 MB
    const size_t needB = (size_t)OUT_DIM * KD2 * sizeof(unsigned short); // 14 MB
    const size_t needBias = 32 * (size_t)OUT_DIM * sizeof(float);        // 128 KB

    if (ws_size >= needA + needB + needBias) {
        static bool lds_attr_set = false;
        if (!lds_attr_set) {
            (void)hipFuncSetAttribute(
                reinterpret_cast<const void*>(&gemm_kernel),
                hipFuncAttributeMaxDynamicSharedMemorySize, GEMM_LDS);
            lds_attr_set = true;
        }
        unsigned short* Aw = (unsigned short*)d_ws;
        unsigned short* Bt = Aw + (size_t)BATCH * KD2;
        float* bias_part = (float*)((char*)d_ws + needA + needB);
        prep_and_repack<<<PREP_BLOCKS + REPACK_BLOCKS + ZERO_BLOCKS, 256, 0, stream>>>(
            x, a, q, coeffs, Aw, Bt, bias_part, out);
        gemm_kernel<<<(BATCH / BM2) * (OUT_DIM / BN2) * KSPLIT, 512, GEMM_LDS, stream>>>(
            Aw, Bt, bias_part, out);
    } else {
        fallback_kernel<<<BATCH, 256, 0, stream>>>(x, a, q, coeffs, out);
    }
}